// Round 1
// baseline (258.900 us; speedup 1.0000x reference)
//
#include <hip/hip_runtime.h>
#include <hip/hip_bf16.h>
#include <stdint.h>

typedef __attribute__((ext_vector_type(8))) short s16x8;
typedef __attribute__((ext_vector_type(8))) unsigned short u16x8;
typedef __attribute__((ext_vector_type(4))) float f32x4;

#define SEQ 2048

__device__ __forceinline__ unsigned short f2b(float x) {
  union { __hip_bfloat16 h; unsigned short u; } cv;
  cv.h = __float2bfloat16(x);
  return cv.u;
}

__device__ __forceinline__ void gload16(const void* g, void* l) {
  __builtin_amdgcn_global_load_lds(
      (const __attribute__((address_space(1))) void*)g,
      (__attribute__((address_space(3))) void*)l, 16, 0, 0);
}

__global__ void cvt_f32_bf16(const float* __restrict__ in,
                             __hip_bfloat16* __restrict__ out, int n4) {
  int i = blockIdx.x * blockDim.x + threadIdx.x;
  if (i >= n4) return;
  float4 v = reinterpret_cast<const float4*>(in)[i];
  ushort4 o;
  o.x = f2b(v.x); o.y = f2b(v.y); o.z = f2b(v.z); o.w = f2b(v.w);
  reinterpret_cast<ushort4*>(out)[i] = o;
}

// C = A[M,K] * B^T (B is [N,K] row-major), + bias[N]
// MODE 0: bf16 out: col<2048 -> qk buffer [M][2048]; col>=2048 -> Vt[b][h][hd][s]
// MODE 1: f32 out [M][N]
template <int MODE>
__global__ __launch_bounds__(256) void gemm_bt(
    const __hip_bfloat16* __restrict__ A, const __hip_bfloat16* __restrict__ B,
    const float* __restrict__ bias, void* __restrict__ Cout,
    __hip_bfloat16* __restrict__ Vt, int M, int N, int K) {
  __shared__ __align__(16) __hip_bfloat16 As[128 * 32];
  __shared__ __align__(16) __hip_bfloat16 Bs[128 * 32];
  const int tid = threadIdx.x;
  const int lane = tid & 63;
  const int w = tid >> 6;
  const int wr = w >> 1, wc = w & 1;
  const int rowg = blockIdx.x * 128;
  const int colg = blockIdx.y * 128;
  const int lr = lane & 15;
  const int lk = (lane >> 4) * 8;
  f32x4 acc[4][4];
#pragma unroll
  for (int m = 0; m < 4; ++m)
#pragma unroll
    for (int n = 0; n < 4; ++n) acc[m][n] = (f32x4){0.f, 0.f, 0.f, 0.f};
  for (int kt = 0; kt < K; kt += 32) {
#pragma unroll
    for (int r = 0; r < 2; ++r) {
      const int idx = r * 256 + tid;
      const int row = idx >> 2;
      const int ko = (idx & 3) * 8;
      gload16(A + (size_t)(rowg + row) * K + kt + ko, As + idx * 8);
      gload16(B + (size_t)(colg + row) * K + kt + ko, Bs + idx * 8);
    }
    __syncthreads();
    s16x8 af[4], bfr[4];
#pragma unroll
    for (int m = 0; m < 4; ++m)
      af[m] = *reinterpret_cast<const s16x8*>(As + (wr * 64 + m * 16 + lr) * 32 + lk);
#pragma unroll
    for (int n = 0; n < 4; ++n)
      bfr[n] = *reinterpret_cast<const s16x8*>(Bs + (wc * 64 + n * 16 + lr) * 32 + lk);
#pragma unroll
    for (int m = 0; m < 4; ++m)
#pragma unroll
      for (int n = 0; n < 4; ++n)
        acc[m][n] = __builtin_amdgcn_mfma_f32_16x16x32_bf16(af[m], bfr[n], acc[m][n], 0, 0, 0);
    __syncthreads();
  }
  const int r0l = (lane >> 4) * 4;
#pragma unroll
  for (int m = 0; m < 4; ++m) {
#pragma unroll
    for (int n = 0; n < 4; ++n) {
      const int col = colg + wc * 64 + n * 16 + lr;
      const int row0 = rowg + wr * 64 + m * 16 + r0l;
      const float bv = bias[col];
      if (MODE == 0) {
        if (col < 2048) {
          __hip_bfloat16* qkb = (__hip_bfloat16*)Cout;
#pragma unroll
          for (int j = 0; j < 4; ++j)
            qkb[(size_t)(row0 + j) * 2048 + col] = __float2bfloat16(acc[m][n][j] + bv);
        } else {
          const int c2 = col - 2048;
          const int bb = row0 >> 11;
          const int s0 = row0 & 2047;
          ushort4 pk;
          unsigned short* pp = (unsigned short*)&pk;
#pragma unroll
          for (int j = 0; j < 4; ++j) pp[j] = f2b(acc[m][n][j] + bv);
          *reinterpret_cast<ushort4*>(
              Vt + ((size_t)(bb * 16 + (c2 >> 6)) * 64 + (c2 & 63)) * 2048 + s0) = pk;
        }
      } else {
        float* o = (float*)Cout;
#pragma unroll
        for (int j = 0; j < 4; ++j)
          o[(size_t)(row0 + j) * N + col] = acc[m][n][j] + bv;
      }
    }
  }
}

// XOR swizzle for [rows][128B] LDS tiles: spreads 16B slots across banks
__device__ __forceinline__ int swz(int row, int byteInRow) {
  return row * 128 + (byteInRow ^ ((row & 7) << 4));
}

__global__ __launch_bounds__(256) void attn_fwd(
    const __hip_bfloat16* __restrict__ qk, const __hip_bfloat16* __restrict__ Vt,
    const float* __restrict__ abias, const void* __restrict__ maskp,
    __hip_bfloat16* __restrict__ O) {
  __shared__ __align__(16) char Qs[64 * 128];
  __shared__ __align__(16) char Ks[64 * 128];
  __shared__ __align__(16) char Vs[64 * 128];
  __shared__ __align__(16) char Ps[4][16 * 128];
  const int tid = threadIdx.x;
  const int lane = tid & 63;
  const int w = tid >> 6;
  const int bh = blockIdx.y;
  const int b = bh >> 4, h = bh & 15;
  const int q0 = blockIdx.x * 64;
  // mask format probe: int32 layout -> word0 is 0/1; bool-byte layout -> 0x01010101
  const int* mi = (const int*)maskp;
  const unsigned char* mbyte = (const unsigned char*)maskp;
  const bool int_fmt = (mi[0] == 0 || mi[0] == 1);
  const int lrow = tid >> 2;
  const int s16 = (tid & 3) * 2;
  {
    const __hip_bfloat16* src = qk + (size_t)(b * SEQ + q0 + lrow) * 2048 + h * 64 + s16 * 8;
    u16x8 g0 = *reinterpret_cast<const u16x8*>(src);
    u16x8 g1 = *reinterpret_cast<const u16x8*>(src + 8);
    *reinterpret_cast<u16x8*>(Qs + swz(lrow, s16 * 16)) = g0;
    *reinterpret_cast<u16x8*>(Qs + swz(lrow, s16 * 16 + 16)) = g1;
  }
  const int lr = lane & 15;
  const int lkB = (lane >> 4) * 16;
  float m_r[4], l_r[4];
  f32x4 oa[4];
#pragma unroll
  for (int j = 0; j < 4; ++j) { m_r[j] = -INFINITY; l_r[j] = 0.f; }
#pragma unroll
  for (int d = 0; d < 4; ++d) oa[d] = (f32x4){0.f, 0.f, 0.f, 0.f};
  // Q frags (wave-local rows; loader above was wave-local too)
  s16x8 aq0 = *reinterpret_cast<const s16x8*>(Qs + swz(w * 16 + lr, lkB));
  s16x8 aq1 = *reinterpret_cast<const s16x8*>(Qs + swz(w * 16 + lr, 64 + lkB));
  const int ntiles = blockIdx.x + 1;
  const int qrow0 = q0 + w * 16 + (lane >> 4) * 4;
  for (int t = 0; t < ntiles; ++t) {
    const int kv0 = t * 64;
    __syncthreads();
    {
      const __hip_bfloat16* ksrc =
          qk + (size_t)(b * SEQ + kv0 + lrow) * 2048 + 1024 + h * 64 + s16 * 8;
      u16x8 g0 = *reinterpret_cast<const u16x8*>(ksrc);
      u16x8 g1 = *reinterpret_cast<const u16x8*>(ksrc + 8);
      const __hip_bfloat16* vsrc =
          Vt + (size_t)(bh * 64 + lrow) * 2048 + kv0 + s16 * 8;
      u16x8 v0 = *reinterpret_cast<const u16x8*>(vsrc);
      u16x8 v1 = *reinterpret_cast<const u16x8*>(vsrc + 8);
      *reinterpret_cast<u16x8*>(Ks + swz(lrow, s16 * 16)) = g0;
      *reinterpret_cast<u16x8*>(Ks + swz(lrow, s16 * 16 + 16)) = g1;
      *reinterpret_cast<u16x8*>(Vs + swz(lrow, s16 * 16)) = v0;
      *reinterpret_cast<u16x8*>(Vs + swz(lrow, s16 * 16 + 16)) = v1;
    }
    __syncthreads();
    // S = Q K^T  (16q x 64kv per wave)
    f32x4 sf[4];
#pragma unroll
    for (int n = 0; n < 4; ++n) {
      s16x8 bk0 = *reinterpret_cast<const s16x8*>(Ks + swz(n * 16 + lr, lkB));
      s16x8 bk1 = *reinterpret_cast<const s16x8*>(Ks + swz(n * 16 + lr, 64 + lkB));
      f32x4 z = (f32x4){0.f, 0.f, 0.f, 0.f};
      z = __builtin_amdgcn_mfma_f32_16x16x32_bf16(aq0, bk0, z, 0, 0, 0);
      z = __builtin_amdgcn_mfma_f32_16x16x32_bf16(aq1, bk1, z, 0, 0, 0);
      sf[n] = z;
    }
    // scale + alibi bias + padding & causal masks
#pragma unroll
    for (int n = 0; n < 4; ++n) {
      const int kv = kv0 + n * 16 + lr;
      const float bv = abias[h * SEQ + kv];
      const bool kval = int_fmt ? (mi[b * SEQ + kv] != 0) : (mbyte[b * SEQ + kv] != 0);
#pragma unroll
      for (int j = 0; j < 4; ++j) {
        float v = sf[n][j] * 0.125f + bv;
        if (!kval || kv > qrow0 + j) v = -1e30f;
        sf[n][j] = v;
      }
    }
    // row max (over n in-lane, then 16-lane group)
    float tm[4];
#pragma unroll
    for (int j = 0; j < 4; ++j)
      tm[j] = fmaxf(fmaxf(sf[0][j], sf[1][j]), fmaxf(sf[2][j], sf[3][j]));
#pragma unroll
    for (int off = 1; off < 16; off <<= 1)
#pragma unroll
      for (int j = 0; j < 4; ++j) tm[j] = fmaxf(tm[j], __shfl_xor(tm[j], off));
    float al[4];
#pragma unroll
    for (int j = 0; j < 4; ++j) {
      float mn = fmaxf(m_r[j], tm[j]);
      al[j] = __expf(m_r[j] - mn);
      m_r[j] = mn;
    }
    float rs[4] = {0.f, 0.f, 0.f, 0.f};
#pragma unroll
    for (int n = 0; n < 4; ++n)
#pragma unroll
      for (int j = 0; j < 4; ++j) {
        float p = __expf(sf[n][j] - m_r[j]);
        sf[n][j] = p;
        rs[j] += p;
      }
#pragma unroll
    for (int off = 1; off < 16; off <<= 1)
#pragma unroll
      for (int j = 0; j < 4; ++j) rs[j] += __shfl_xor(rs[j], off);
#pragma unroll
    for (int j = 0; j < 4; ++j) l_r[j] = l_r[j] * al[j] + rs[j];
#pragma unroll
    for (int d = 0; d < 4; ++d)
#pragma unroll
      for (int j = 0; j < 4; ++j) oa[d][j] *= al[j];
    // P -> LDS (per-wave region, swizzled), then PV MFMA
    char* pw = Ps[w];
#pragma unroll
    for (int n = 0; n < 4; ++n)
#pragma unroll
      for (int j = 0; j < 4; ++j) {
        const int qr = (lane >> 4) * 4 + j;
        *reinterpret_cast<unsigned short*>(pw + swz(qr, (n * 16 + lr) * 2)) = f2b(sf[n][j]);
      }
    s16x8 pa0 = *reinterpret_cast<const s16x8*>(pw + swz(lr, lkB));
    s16x8 pa1 = *reinterpret_cast<const s16x8*>(pw + swz(lr, 64 + lkB));
#pragma unroll
    for (int d = 0; d < 4; ++d) {
      s16x8 bv0 = *reinterpret_cast<const s16x8*>(Vs + swz(d * 16 + lr, lkB));
      s16x8 bv1 = *reinterpret_cast<const s16x8*>(Vs + swz(d * 16 + lr, 64 + lkB));
      oa[d] = __builtin_amdgcn_mfma_f32_16x16x32_bf16(pa0, bv0, oa[d], 0, 0, 0);
      oa[d] = __builtin_amdgcn_mfma_f32_16x16x32_bf16(pa1, bv1, oa[d], 0, 0, 0);
    }
  }
#pragma unroll
  for (int j = 0; j < 4; ++j) l_r[j] = 1.0f / l_r[j];
#pragma unroll
  for (int d = 0; d < 4; ++d)
#pragma unroll
    for (int j = 0; j < 4; ++j) {
      const size_t r = (size_t)(b * SEQ + qrow0 + j);
      O[r * 1024 + h * 64 + d * 16 + lr] = __float2bfloat16(oa[d][j] * l_r[j]);
    }
}

extern "C" void kernel_launch(void* const* d_in, const int* in_sizes, int n_in,
                              void* d_out, int out_size, void* d_ws, size_t ws_size,
                              hipStream_t stream) {
  const float* x     = (const float*)d_in[0];
  const float* wqkv  = (const float*)d_in[1];
  const float* bqkv  = (const float*)d_in[2];
  const float* wout  = (const float*)d_in[3];
  const float* bout  = (const float*)d_in[4];
  const float* abias = (const float*)d_in[5];
  const void*  mask  = d_in[6];

  __hip_bfloat16* ws  = (__hip_bfloat16*)d_ws;
  __hip_bfloat16* xb  = ws;              // x bf16            [4096][1024]  (8 MB)
  __hip_bfloat16* wqb = ws + 4194304;    // Wqkv bf16         [3072][1024]  (6 MB)
  __hip_bfloat16* owb = ws + 7340032;    // out_w bf16        [1024][1024]  (2 MB)
  __hip_bfloat16* qkb = ws + 8388608;    // q|k bf16          [4096][2048]  (16 MB)
  __hip_bfloat16* vtb = ws + 16777216;   // V^T bf16          [2][16][64][2048] (8 MB)
  __hip_bfloat16* aob = xb;              // attn out bf16 overlays xb (dead after gemm1)

  cvt_f32_bf16<<<4096, 256, 0, stream>>>(x, xb, 1048576);
  cvt_f32_bf16<<<3072, 256, 0, stream>>>(wqkv, wqb, 786432);
  cvt_f32_bf16<<<1024, 256, 0, stream>>>(wout, owb, 262144);
  gemm_bt<0><<<dim3(32, 24), 256, 0, stream>>>(xb, wqb, bqkv, (void*)qkb, vtb,
                                               4096, 3072, 1024);
  attn_fwd<<<dim3(32, 32), 256, 0, stream>>>(qkb, vtb, abias, mask, aob);
  gemm_bt<1><<<dim3(32, 8), 256, 0, stream>>>(aob, owb, bout, d_out,
                                              (__hip_bfloat16*)nullptr, 4096, 1024, 1024);
}

// Round 2
// 208.213 us; speedup vs baseline: 1.2434x; 1.2434x over previous
//
#include <hip/hip_runtime.h>
#include <hip/hip_bf16.h>
#include <stdint.h>

typedef __attribute__((ext_vector_type(8))) short s16x8;
typedef __attribute__((ext_vector_type(8))) unsigned short u16x8;
typedef __attribute__((ext_vector_type(4))) float f32x4;

#define SEQ 2048

__device__ __forceinline__ unsigned short f2b(float x) {
  union { __hip_bfloat16 h; unsigned short u; } cv;
  cv.h = __float2bfloat16(x);
  return cv.u;
}

__device__ __forceinline__ void gload16(const void* g, void* l) {
  __builtin_amdgcn_global_load_lds(
      (const __attribute__((address_space(1))) void*)g,
      (__attribute__((address_space(3))) void*)l, 16, 0, 0);
}

__global__ void cvt_f32_bf16(const float* __restrict__ in,
                             __hip_bfloat16* __restrict__ out, int n4) {
  int i = blockIdx.x * blockDim.x + threadIdx.x;
  if (i >= n4) return;
  float4 v = reinterpret_cast<const float4*>(in)[i];
  ushort4 o;
  o.x = f2b(v.x); o.y = f2b(v.y); o.z = f2b(v.z); o.w = f2b(v.w);
  reinterpret_cast<ushort4*>(out)[i] = o;
}

// C = A[M,K] * B^T (B is [N,K] row-major), + bias[N]
// MODE 0: bf16 out: col<2048 -> qk buffer [M][2048]; col>=2048 -> Vt[b][h][hd][s]
// MODE 1: f32 out [M][N]
template <int MODE>
__global__ __launch_bounds__(256) void gemm_bt(
    const __hip_bfloat16* __restrict__ A, const __hip_bfloat16* __restrict__ B,
    const float* __restrict__ bias, void* __restrict__ Cout,
    __hip_bfloat16* __restrict__ Vt, int M, int N, int K) {
  __shared__ __align__(16) __hip_bfloat16 As[128 * 32];
  __shared__ __align__(16) __hip_bfloat16 Bs[128 * 32];
  const int tid = threadIdx.x;
  const int lane = tid & 63;
  const int w = tid >> 6;
  const int wr = w >> 1, wc = w & 1;
  const int rowg = blockIdx.x * 128;
  const int colg = blockIdx.y * 128;
  const int lr = lane & 15;
  const int lk = (lane >> 4) * 8;
  f32x4 acc[4][4];
#pragma unroll
  for (int m = 0; m < 4; ++m)
#pragma unroll
    for (int n = 0; n < 4; ++n) acc[m][n] = (f32x4){0.f, 0.f, 0.f, 0.f};
  for (int kt = 0; kt < K; kt += 32) {
#pragma unroll
    for (int r = 0; r < 2; ++r) {
      const int idx = r * 256 + tid;
      const int row = idx >> 2;
      const int ko = (idx & 3) * 8;
      gload16(A + (size_t)(rowg + row) * K + kt + ko, As + idx * 8);
      gload16(B + (size_t)(colg + row) * K + kt + ko, Bs + idx * 8);
    }
    __syncthreads();
    s16x8 af[4], bfr[4];
#pragma unroll
    for (int m = 0; m < 4; ++m)
      af[m] = *reinterpret_cast<const s16x8*>(As + (wr * 64 + m * 16 + lr) * 32 + lk);
#pragma unroll
    for (int n = 0; n < 4; ++n)
      bfr[n] = *reinterpret_cast<const s16x8*>(Bs + (wc * 64 + n * 16 + lr) * 32 + lk);
#pragma unroll
    for (int m = 0; m < 4; ++m)
#pragma unroll
      for (int n = 0; n < 4; ++n)
        acc[m][n] = __builtin_amdgcn_mfma_f32_16x16x32_bf16(af[m], bfr[n], acc[m][n], 0, 0, 0);
    __syncthreads();
  }
  const int r0l = (lane >> 4) * 4;
#pragma unroll
  for (int m = 0; m < 4; ++m) {
#pragma unroll
    for (int n = 0; n < 4; ++n) {
      const int col = colg + wc * 64 + n * 16 + lr;
      const int row0 = rowg + wr * 64 + m * 16 + r0l;
      const float bv = bias[col];
      if (MODE == 0) {
        if (col < 2048) {
          __hip_bfloat16* qkb = (__hip_bfloat16*)Cout;
#pragma unroll
          for (int j = 0; j < 4; ++j)
            qkb[(size_t)(row0 + j) * 2048 + col] = __float2bfloat16(acc[m][n][j] + bv);
        } else {
          const int c2 = col - 2048;
          const int bb = row0 >> 11;
          const int s0 = row0 & 2047;
          ushort4 pk;
          unsigned short* pp = (unsigned short*)&pk;
#pragma unroll
          for (int j = 0; j < 4; ++j) pp[j] = f2b(acc[m][n][j] + bv);
          *reinterpret_cast<ushort4*>(
              Vt + ((size_t)(bb * 16 + (c2 >> 6)) * 64 + (c2 & 63)) * 2048 + s0) = pk;
        }
      } else {
        float* o = (float*)Cout;
#pragma unroll
        for (int j = 0; j < 4; ++j)
          o[(size_t)(row0 + j) * N + col] = acc[m][n][j] + bv;
      }
    }
  }
}

// XOR swizzle for [rows][128B] LDS tiles: spreads 16B slots across banks
__device__ __forceinline__ int swz(int row, int byteInRow) {
  return row * 128 + (byteInRow ^ ((row & 7) << 4));
}

__global__ __launch_bounds__(256) void attn_fwd(
    const __hip_bfloat16* __restrict__ qk, const __hip_bfloat16* __restrict__ Vt,
    const float* __restrict__ abias, const void* __restrict__ maskp,
    __hip_bfloat16* __restrict__ O) {
  __shared__ __align__(16) char Qs[64 * 128];
  __shared__ __align__(16) char Ks[64 * 128];
  __shared__ __align__(16) char Vs[64 * 128];
  __shared__ __align__(16) char Ps[4][16 * 128];
  __shared__ float Bm[64];
  const int tid = threadIdx.x;
  const int lane = tid & 63;
  const int w = tid >> 6;
  const int bh = blockIdx.y;
  const int b = bh >> 4, h = bh & 15;
  const int qt = gridDim.x - 1 - blockIdx.x;  // heavy (long-loop) blocks dispatch first
  const int q0 = qt * 64;
  // mask format probe: int32 layout -> word0 is 0/1; bool-byte layout -> 0x01010101
  const int* mi = (const int*)maskp;
  const unsigned char* mbyte = (const unsigned char*)maskp;
  const bool int_fmt = (mi[0] == 0 || mi[0] == 1);
  const int lrow = tid >> 2;
  const int s16 = (tid & 3) * 2;
  {
    // stage Q: wave w's threads stage exactly rows [w*16, w*16+16) -> wave-local, no barrier
    const __hip_bfloat16* src = qk + (size_t)(b * SEQ + q0 + lrow) * 2048 + h * 64 + s16 * 8;
    u16x8 g0 = *reinterpret_cast<const u16x8*>(src);
    u16x8 g1 = *reinterpret_cast<const u16x8*>(src + 8);
    *reinterpret_cast<u16x8*>(Qs + swz(lrow, s16 * 16)) = g0;
    *reinterpret_cast<u16x8*>(Qs + swz(lrow, s16 * 16 + 16)) = g1;
  }
  const int lr = lane & 15;
  const int lkB = (lane >> 4) * 16;
  float m_r[4], l_r[4];
  f32x4 oa[4];
#pragma unroll
  for (int j = 0; j < 4; ++j) { m_r[j] = -INFINITY; l_r[j] = 0.f; }
#pragma unroll
  for (int d = 0; d < 4; ++d) oa[d] = (f32x4){0.f, 0.f, 0.f, 0.f};
  s16x8 aq0 = *reinterpret_cast<const s16x8*>(Qs + swz(w * 16 + lr, lkB));
  s16x8 aq1 = *reinterpret_cast<const s16x8*>(Qs + swz(w * 16 + lr, 64 + lkB));
  const int ntiles = qt + 1;
  const int qrow0 = q0 + w * 16 + (lane >> 4) * 4;

  const __hip_bfloat16* kbase = qk + (size_t)b * SEQ * 2048 + 1024 + h * 64 + s16 * 8;
  const __hip_bfloat16* vbase = Vt + (size_t)(bh * 64 + lrow) * 2048 + s16 * 8;

  // register prefetch state (T14 async-STAGE: issue early, LDS-write late)
  u16x8 kp0, kp1, vp0, vp1;
  float bmv = 0.f;
#define ISSUE_TILE(T)                                                            \
  {                                                                              \
    const int kv0_ = (T) * 64;                                                   \
    const __hip_bfloat16* ksrc_ = kbase + (size_t)(kv0_ + lrow) * 2048;          \
    kp0 = *reinterpret_cast<const u16x8*>(ksrc_);                                \
    kp1 = *reinterpret_cast<const u16x8*>(ksrc_ + 8);                            \
    const __hip_bfloat16* vsrc_ = vbase + kv0_;                                  \
    vp0 = *reinterpret_cast<const u16x8*>(vsrc_);                                \
    vp1 = *reinterpret_cast<const u16x8*>(vsrc_ + 8);                            \
    if (tid < 64) {                                                              \
      const int kv_ = kv0_ + tid;                                                \
      const bool kv_ok_ =                                                        \
          int_fmt ? (mi[b * SEQ + kv_] != 0) : (mbyte[b * SEQ + kv_] != 0);      \
      bmv = kv_ok_ ? abias[h * SEQ + kv_] : -1e30f;                              \
    }                                                                            \
  }

  ISSUE_TILE(0);
  for (int t = 0; t < ntiles; ++t) {
    const int kv0 = t * 64;
    __syncthreads();  // all waves done reading previous Ks/Vs
    *reinterpret_cast<u16x8*>(Ks + swz(lrow, s16 * 16)) = kp0;
    *reinterpret_cast<u16x8*>(Ks + swz(lrow, s16 * 16 + 16)) = kp1;
    *reinterpret_cast<u16x8*>(Vs + swz(lrow, s16 * 16)) = vp0;
    *reinterpret_cast<u16x8*>(Vs + swz(lrow, s16 * 16 + 16)) = vp1;
    if (tid < 64) Bm[tid] = bmv;
    __syncthreads();
    if (t + 1 < ntiles) ISSUE_TILE(t + 1);  // latency hides under this tile's compute

    // S = Q K^T  (16q x 64kv per wave)
    f32x4 sf[4];
#pragma unroll
    for (int n = 0; n < 4; ++n) {
      s16x8 bk0 = *reinterpret_cast<const s16x8*>(Ks + swz(n * 16 + lr, lkB));
      s16x8 bk1 = *reinterpret_cast<const s16x8*>(Ks + swz(n * 16 + lr, 64 + lkB));
      f32x4 z = (f32x4){0.f, 0.f, 0.f, 0.f};
      z = __builtin_amdgcn_mfma_f32_16x16x32_bf16(aq0, bk0, z, 0, 0, 0);
      z = __builtin_amdgcn_mfma_f32_16x16x32_bf16(aq1, bk1, z, 0, 0, 0);
      sf[n] = z;
    }
    // scale + (bias|padding) from LDS + causal mask
#pragma unroll
    for (int n = 0; n < 4; ++n) {
      const int kv = kv0 + n * 16 + lr;
      const float bv = Bm[n * 16 + lr];
#pragma unroll
      for (int j = 0; j < 4; ++j) {
        float v = fmaf(sf[n][j], 0.125f, bv);
        if (kv > qrow0 + j) v = -1e30f;
        sf[n][j] = v;
      }
    }
    // row max (over n in-lane, then 16-lane group)
    float tm[4];
#pragma unroll
    for (int j = 0; j < 4; ++j)
      tm[j] = fmaxf(fmaxf(sf[0][j], sf[1][j]), fmaxf(sf[2][j], sf[3][j]));
#pragma unroll
    for (int off = 1; off < 16; off <<= 1)
#pragma unroll
      for (int j = 0; j < 4; ++j) tm[j] = fmaxf(tm[j], __shfl_xor(tm[j], off));
    float al[4];
#pragma unroll
    for (int j = 0; j < 4; ++j) {
      float mn = fmaxf(m_r[j], tm[j]);
      al[j] = __expf(m_r[j] - mn);
      m_r[j] = mn;
    }
    float rs[4] = {0.f, 0.f, 0.f, 0.f};
#pragma unroll
    for (int n = 0; n < 4; ++n)
#pragma unroll
      for (int j = 0; j < 4; ++j) {
        float p = __expf(sf[n][j] - m_r[j]);
        sf[n][j] = p;
        rs[j] += p;
      }
#pragma unroll
    for (int off = 1; off < 16; off <<= 1)
#pragma unroll
      for (int j = 0; j < 4; ++j) rs[j] += __shfl_xor(rs[j], off);
#pragma unroll
    for (int j = 0; j < 4; ++j) l_r[j] = l_r[j] * al[j] + rs[j];
#pragma unroll
    for (int d = 0; d < 4; ++d)
#pragma unroll
      for (int j = 0; j < 4; ++j) oa[d][j] *= al[j];
    // P -> LDS (per-wave region, swizzled), then PV MFMA
    char* pw = Ps[w];
#pragma unroll
    for (int n = 0; n < 4; ++n)
#pragma unroll
      for (int j = 0; j < 4; ++j) {
        const int qr = (lane >> 4) * 4 + j;
        *reinterpret_cast<unsigned short*>(pw + swz(qr, (n * 16 + lr) * 2)) = f2b(sf[n][j]);
      }
    s16x8 pa0 = *reinterpret_cast<const s16x8*>(pw + swz(lr, lkB));
    s16x8 pa1 = *reinterpret_cast<const s16x8*>(pw + swz(lr, 64 + lkB));
#pragma unroll
    for (int d = 0; d < 4; ++d) {
      s16x8 bv0 = *reinterpret_cast<const s16x8*>(Vs + swz(d * 16 + lr, lkB));
      s16x8 bv1 = *reinterpret_cast<const s16x8*>(Vs + swz(d * 16 + lr, 64 + lkB));
      oa[d] = __builtin_amdgcn_mfma_f32_16x16x32_bf16(pa0, bv0, oa[d], 0, 0, 0);
      oa[d] = __builtin_amdgcn_mfma_f32_16x16x32_bf16(pa1, bv1, oa[d], 0, 0, 0);
    }
  }
#pragma unroll
  for (int j = 0; j < 4; ++j) l_r[j] = 1.0f / l_r[j];
#pragma unroll
  for (int d = 0; d < 4; ++d)
#pragma unroll
    for (int j = 0; j < 4; ++j) {
      const size_t r = (size_t)(b * SEQ + qrow0 + j);
      O[r * 1024 + h * 64 + d * 16 + lr] = __float2bfloat16(oa[d][j] * l_r[j]);
    }
#undef ISSUE_TILE
}

extern "C" void kernel_launch(void* const* d_in, const int* in_sizes, int n_in,
                              void* d_out, int out_size, void* d_ws, size_t ws_size,
                              hipStream_t stream) {
  const float* x     = (const float*)d_in[0];
  const float* wqkv  = (const float*)d_in[1];
  const float* bqkv  = (const float*)d_in[2];
  const float* wout  = (const float*)d_in[3];
  const float* bout  = (const float*)d_in[4];
  const float* abias = (const float*)d_in[5];
  const void*  mask  = d_in[6];

  __hip_bfloat16* ws  = (__hip_bfloat16*)d_ws;
  __hip_bfloat16* xb  = ws;              // x bf16            [4096][1024]  (8 MB)
  __hip_bfloat16* wqb = ws + 4194304;    // Wqkv bf16         [3072][1024]  (6 MB)
  __hip_bfloat16* owb = ws + 7340032;    // out_w bf16        [1024][1024]  (2 MB)
  __hip_bfloat16* qkb = ws + 8388608;    // q|k bf16          [4096][2048]  (16 MB)
  __hip_bfloat16* vtb = ws + 16777216;   // V^T bf16          [2][16][64][2048] (8 MB)
  __hip_bfloat16* aob = xb;              // attn out bf16 overlays xb (dead after gemm1)

  cvt_f32_bf16<<<4096, 256, 0, stream>>>(x, xb, 1048576);
  cvt_f32_bf16<<<3072, 256, 0, stream>>>(wqkv, wqb, 786432);
  cvt_f32_bf16<<<1024, 256, 0, stream>>>(wout, owb, 262144);
  gemm_bt<0><<<dim3(32, 24), 256, 0, stream>>>(xb, wqb, bqkv, (void*)qkb, vtb,
                                               4096, 3072, 1024);
  attn_fwd<<<dim3(32, 32), 256, 0, stream>>>(qkb, vtb, abias, mask, aob);
  gemm_bt<1><<<dim3(32, 8), 256, 0, stream>>>(aob, owb, bout, d_out,
                                              (__hip_bfloat16*)nullptr, 4096, 1024, 1024);
}

// Round 3
// 154.820 us; speedup vs baseline: 1.6723x; 1.3449x over previous
//
#include <hip/hip_runtime.h>
#include <hip/hip_bf16.h>
#include <stdint.h>

typedef __attribute__((ext_vector_type(8))) short s16x8;
typedef __attribute__((ext_vector_type(8))) unsigned short u16x8;
typedef __attribute__((ext_vector_type(4))) float f32x4;

#define SEQ 2048
#define LOG2E 1.44269504088896f

__device__ __forceinline__ unsigned short f2b(float x) {
  union { __hip_bfloat16 h; unsigned short u; } cv;
  cv.h = __float2bfloat16(x);
  return cv.u;
}

__device__ __forceinline__ float exp2fast(float x) {
  float r;
  asm("v_exp_f32 %0, %1" : "=v"(r) : "v"(x));
  return r;
}

__device__ __forceinline__ void gload16(const void* g, void* l) {
  __builtin_amdgcn_global_load_lds(
      (const __attribute__((address_space(1))) void*)g,
      (__attribute__((address_space(3))) void*)l, 16, 0, 0);
}

__global__ void cvt_f32_bf16(const float* __restrict__ in,
                             __hip_bfloat16* __restrict__ out, int n4) {
  int i = blockIdx.x * blockDim.x + threadIdx.x;
  if (i >= n4) return;
  float4 v = reinterpret_cast<const float4*>(in)[i];
  ushort4 o;
  o.x = f2b(v.x); o.y = f2b(v.y); o.z = f2b(v.z); o.w = f2b(v.w);
  reinterpret_cast<ushort4*>(out)[i] = o;
}

// C = A[M,K] * B^T (B is [N,K] row-major), + bias[N]
// MODE 0: bf16 out: col<2048 -> qk buffer [M][2048]; col>=2048 -> Vt[b][h][hd][s]
// MODE 1: f32 out [M][N]
template <int MODE>
__global__ __launch_bounds__(256) void gemm_bt(
    const __hip_bfloat16* __restrict__ A, const __hip_bfloat16* __restrict__ B,
    const float* __restrict__ bias, void* __restrict__ Cout,
    __hip_bfloat16* __restrict__ Vt, int M, int N, int K) {
  __shared__ __align__(16) __hip_bfloat16 As[128 * 32];
  __shared__ __align__(16) __hip_bfloat16 Bs[128 * 32];
  const int tid = threadIdx.x;
  const int lane = tid & 63;
  const int w = tid >> 6;
  const int wr = w >> 1, wc = w & 1;
  const int rowg = blockIdx.x * 128;
  const int colg = blockIdx.y * 128;
  const int lr = lane & 15;
  const int lk = (lane >> 4) * 8;
  f32x4 acc[4][4];
#pragma unroll
  for (int m = 0; m < 4; ++m)
#pragma unroll
    for (int n = 0; n < 4; ++n) acc[m][n] = (f32x4){0.f, 0.f, 0.f, 0.f};
  for (int kt = 0; kt < K; kt += 32) {
#pragma unroll
    for (int r = 0; r < 2; ++r) {
      const int idx = r * 256 + tid;
      const int row = idx >> 2;
      const int ko = (idx & 3) * 8;
      gload16(A + (size_t)(rowg + row) * K + kt + ko, As + idx * 8);
      gload16(B + (size_t)(colg + row) * K + kt + ko, Bs + idx * 8);
    }
    __syncthreads();
    s16x8 af[4], bfr[4];
#pragma unroll
    for (int m = 0; m < 4; ++m)
      af[m] = *reinterpret_cast<const s16x8*>(As + (wr * 64 + m * 16 + lr) * 32 + lk);
#pragma unroll
    for (int n = 0; n < 4; ++n)
      bfr[n] = *reinterpret_cast<const s16x8*>(Bs + (wc * 64 + n * 16 + lr) * 32 + lk);
#pragma unroll
    for (int m = 0; m < 4; ++m)
#pragma unroll
      for (int n = 0; n < 4; ++n)
        acc[m][n] = __builtin_amdgcn_mfma_f32_16x16x32_bf16(af[m], bfr[n], acc[m][n], 0, 0, 0);
    __syncthreads();
  }
  const int r0l = (lane >> 4) * 4;
#pragma unroll
  for (int m = 0; m < 4; ++m) {
#pragma unroll
    for (int n = 0; n < 4; ++n) {
      const int col = colg + wc * 64 + n * 16 + lr;
      const int row0 = rowg + wr * 64 + m * 16 + r0l;
      const float bv = bias[col];
      if (MODE == 0) {
        if (col < 2048) {
          __hip_bfloat16* qkb = (__hip_bfloat16*)Cout;
#pragma unroll
          for (int j = 0; j < 4; ++j)
            qkb[(size_t)(row0 + j) * 2048 + col] = __float2bfloat16(acc[m][n][j] + bv);
        } else {
          const int c2 = col - 2048;
          const int bb = row0 >> 11;
          const int s0 = row0 & 2047;
          ushort4 pk;
          unsigned short* pp = (unsigned short*)&pk;
#pragma unroll
          for (int j = 0; j < 4; ++j) pp[j] = f2b(acc[m][n][j] + bv);
          *reinterpret_cast<ushort4*>(
              Vt + ((size_t)(bb * 16 + (c2 >> 6)) * 64 + (c2 & 63)) * 2048 + s0) = pk;
        }
      } else {
        float* o = (float*)Cout;
#pragma unroll
        for (int j = 0; j < 4; ++j)
          o[(size_t)(row0 + j) * N + col] = acc[m][n][j] + bv;
      }
    }
  }
}

// XOR swizzle for [rows][128B] LDS tiles: spreads 16B slots across banks
__device__ __forceinline__ int swz(int row, int byteInRow) {
  return row * 128 + (byteInRow ^ ((row & 7) << 4));
}

__device__ __forceinline__ void attn_tile(
    const char* Ks, const char* Vs, char* pw, const float* Bm,
    s16x8 aq0, s16x8 aq1, int lane, int kv0, int qrow0, bool causal,
    float* m_r, float* l_r, f32x4* oa) {
  const int lr = lane & 15;
  const int lkB = (lane >> 4) * 16;
  const float SCALE2 = 0.125f * LOG2E;
  // S = Q K^T (16q x 64kv)
  f32x4 sf[4];
#pragma unroll
  for (int n = 0; n < 4; ++n) {
    s16x8 bk0 = *reinterpret_cast<const s16x8*>(Ks + swz(n * 16 + lr, lkB));
    s16x8 bk1 = *reinterpret_cast<const s16x8*>(Ks + swz(n * 16 + lr, 64 + lkB));
    f32x4 z = (f32x4){0.f, 0.f, 0.f, 0.f};
    z = __builtin_amdgcn_mfma_f32_16x16x32_bf16(aq0, bk0, z, 0, 0, 0);
    z = __builtin_amdgcn_mfma_f32_16x16x32_bf16(aq1, bk1, z, 0, 0, 0);
    sf[n] = z;
  }
  // scale + (bias|padding) in exp2 domain
#pragma unroll
  for (int n = 0; n < 4; ++n) {
    const float bv = Bm[n * 16 + lr];
#pragma unroll
    for (int j = 0; j < 4; ++j) sf[n][j] = fmaf(sf[n][j], SCALE2, bv);
  }
  if (causal) {  // only the diagonal tile needs causal masking
#pragma unroll
    for (int n = 0; n < 4; ++n) {
      const int kv = kv0 + n * 16 + lr;
#pragma unroll
      for (int j = 0; j < 4; ++j)
        if (kv > qrow0 + j) sf[n][j] = -1e30f;
    }
  }
  // row max
  float tm[4];
#pragma unroll
  for (int j = 0; j < 4; ++j)
    tm[j] = fmaxf(fmaxf(sf[0][j], sf[1][j]), fmaxf(sf[2][j], sf[3][j]));
#pragma unroll
  for (int off = 1; off < 16; off <<= 1)
#pragma unroll
    for (int j = 0; j < 4; ++j) tm[j] = fmaxf(tm[j], __shfl_xor(tm[j], off));
  float al[4];
#pragma unroll
  for (int j = 0; j < 4; ++j) {
    float mn = fmaxf(m_r[j], tm[j]);
    al[j] = exp2fast(m_r[j] - mn);
    m_r[j] = mn;
  }
  float rs[4] = {0.f, 0.f, 0.f, 0.f};
#pragma unroll
  for (int n = 0; n < 4; ++n)
#pragma unroll
    for (int j = 0; j < 4; ++j) {
      float p = exp2fast(sf[n][j] - m_r[j]);
      sf[n][j] = p;
      rs[j] += p;
    }
#pragma unroll
  for (int off = 1; off < 16; off <<= 1)
#pragma unroll
    for (int j = 0; j < 4; ++j) rs[j] += __shfl_xor(rs[j], off);
#pragma unroll
  for (int j = 0; j < 4; ++j) l_r[j] = l_r[j] * al[j] + rs[j];
#pragma unroll
  for (int d = 0; d < 4; ++d)
#pragma unroll
    for (int j = 0; j < 4; ++j) oa[d][j] *= al[j];
  // P -> per-wave LDS, then PV
#pragma unroll
  for (int n = 0; n < 4; ++n)
#pragma unroll
    for (int j = 0; j < 4; ++j) {
      const int qr = (lane >> 4) * 4 + j;
      *reinterpret_cast<unsigned short*>(pw + swz(qr, (n * 16 + lr) * 2)) = f2b(sf[n][j]);
    }
  s16x8 pa0 = *reinterpret_cast<const s16x8*>(pw + swz(lr, lkB));
  s16x8 pa1 = *reinterpret_cast<const s16x8*>(pw + swz(lr, 64 + lkB));
#pragma unroll
  for (int d = 0; d < 4; ++d) {
    s16x8 bv0 = *reinterpret_cast<const s16x8*>(Vs + swz(d * 16 + lr, lkB));
    s16x8 bv1 = *reinterpret_cast<const s16x8*>(Vs + swz(d * 16 + lr, 64 + lkB));
    oa[d] = __builtin_amdgcn_mfma_f32_16x16x32_bf16(pa0, bv0, oa[d], 0, 0, 0);
    oa[d] = __builtin_amdgcn_mfma_f32_16x16x32_bf16(pa1, bv1, oa[d], 0, 0, 0);
  }
}

// Causal-paired flash attention: block = q-tile pair (p, 31-p), 8 waves.
// Waves 0-3 -> heavy tile (31-p), waves 4-7 -> light tile (p). Waves w and
// w+4 share a SIMD -> per-SIMD work = nt_h + nt_l = 33 tiles, uniform
// across ALL SIMDs (no causal tail). K/V staged once per pair.
__global__ __launch_bounds__(512) void attn_fwd(
    const __hip_bfloat16* __restrict__ qk, const __hip_bfloat16* __restrict__ Vt,
    const float* __restrict__ abias, const void* __restrict__ maskp,
    __hip_bfloat16* __restrict__ O) {
  __shared__ __align__(16) char Ks[64 * 128];
  __shared__ __align__(16) char Vs[64 * 128];
  __shared__ __align__(16) char Ps[8][16 * 128];
  __shared__ float Bm[64];
  const int tid = threadIdx.x;
  const int lane = tid & 63;
  const int w = tid >> 6;
  const int p = blockIdx.x;
  const int bh = blockIdx.y;
  const int b = bh >> 4, h = bh & 15;
  const int qt = (w < 4) ? (31 - p) : p;  // 64-row q-tile index
  const int wsub = w & 3;
  const int row0 = qt * 64 + wsub * 16;   // wave's 16 q rows
  const int my_nt = qt + 1;               // kv tiles this wave needs
  const int NT = 32 - p;                  // block loop count (= heavy nt)
  // mask format probe: int32 layout -> word0 is 0/1; bool-byte layout -> 0x01010101
  const int* mi = (const int*)maskp;
  const unsigned char* mbyte = (const unsigned char*)maskp;
  const bool int_fmt = (mi[0] == 0 || mi[0] == 1);
  const int lr = lane & 15;
  // Q fragments straight from global (L2-hot; once per kernel)
  const __hip_bfloat16* qrow =
      qk + (size_t)(b * SEQ + row0 + lr) * 2048 + h * 64 + (lane >> 4) * 8;
  s16x8 aq0 = *reinterpret_cast<const s16x8*>(qrow);
  s16x8 aq1 = *reinterpret_cast<const s16x8*>(qrow + 32);
  float m_r[4], l_r[4];
  f32x4 oa[4];
#pragma unroll
  for (int j = 0; j < 4; ++j) { m_r[j] = -INFINITY; l_r[j] = 0.f; }
#pragma unroll
  for (int d = 0; d < 4; ++d) oa[d] = (f32x4){0.f, 0.f, 0.f, 0.f};
  const int qrow0 = row0 + (lane >> 4) * 4;
  // staging: 512 threads cover 64 rows x 128B (one 16B chunk each)
  const int srow = tid >> 3;
  const int sbyte = (tid & 7) * 16;
  const __hip_bfloat16* kbase =
      qk + (size_t)b * SEQ * 2048 + 1024 + h * 64 + (tid & 7) * 8;
  const __hip_bfloat16* vbase = Vt + (size_t)(bh * 64 + srow) * 2048 + (tid & 7) * 8;
  u16x8 kp, vp;
  float bmv = 0.f;
#define ISSUE_TILE(T)                                                          \
  {                                                                            \
    const int kv0_ = (T) * 64;                                                 \
    kp = *reinterpret_cast<const u16x8*>(kbase + (size_t)(kv0_ + srow) * 2048);\
    vp = *reinterpret_cast<const u16x8*>(vbase + kv0_);                        \
    if (tid < 64) {                                                            \
      const int kv_ = kv0_ + tid;                                              \
      const bool ok_ =                                                         \
          int_fmt ? (mi[b * SEQ + kv_] != 0) : (mbyte[b * SEQ + kv_] != 0);    \
      bmv = ok_ ? abias[h * SEQ + kv_] * LOG2E : -1e30f;                       \
    }                                                                          \
  }
  ISSUE_TILE(0);
  for (int t = 0; t < NT; ++t) {
    const int kv0 = t * 64;
    __syncthreads();  // all waves done reading previous Ks/Vs (drains prefetch vmcnt)
    *reinterpret_cast<u16x8*>(Ks + swz(srow, sbyte)) = kp;
    *reinterpret_cast<u16x8*>(Vs + swz(srow, sbyte)) = vp;
    if (tid < 64) Bm[tid] = bmv;
    __syncthreads();
    if (t + 1 < NT) ISSUE_TILE(t + 1);  // latency hides under this tile's compute
    if (t < my_nt)
      attn_tile(Ks, Vs, Ps[w], Bm, aq0, aq1, lane, kv0, qrow0,
                t == my_nt - 1, m_r, l_r, oa);
  }
#undef ISSUE_TILE
#pragma unroll
  for (int j = 0; j < 4; ++j) l_r[j] = 1.0f / l_r[j];
#pragma unroll
  for (int d = 0; d < 4; ++d)
#pragma unroll
    for (int j = 0; j < 4; ++j) {
      const size_t r = (size_t)(b * SEQ + qrow0 + j);
      O[r * 1024 + h * 64 + d * 16 + lr] = __float2bfloat16(oa[d][j] * l_r[j]);
    }
}

extern "C" void kernel_launch(void* const* d_in, const int* in_sizes, int n_in,
                              void* d_out, int out_size, void* d_ws, size_t ws_size,
                              hipStream_t stream) {
  const float* x     = (const float*)d_in[0];
  const float* wqkv  = (const float*)d_in[1];
  const float* bqkv  = (const float*)d_in[2];
  const float* wout  = (const float*)d_in[3];
  const float* bout  = (const float*)d_in[4];
  const float* abias = (const float*)d_in[5];
  const void*  mask  = d_in[6];

  __hip_bfloat16* ws  = (__hip_bfloat16*)d_ws;
  __hip_bfloat16* xb  = ws;              // x bf16            [4096][1024]  (8 MB)
  __hip_bfloat16* wqb = ws + 4194304;    // Wqkv bf16         [3072][1024]  (6 MB)
  __hip_bfloat16* owb = ws + 7340032;    // out_w bf16        [1024][1024]  (2 MB)
  __hip_bfloat16* qkb = ws + 8388608;    // q|k bf16          [4096][2048]  (16 MB)
  __hip_bfloat16* vtb = ws + 16777216;   // V^T bf16          [2][16][64][2048] (8 MB)
  __hip_bfloat16* aob = xb;              // attn out bf16 overlays xb (dead after gemm1)

  cvt_f32_bf16<<<4096, 256, 0, stream>>>(x, xb, 1048576);
  cvt_f32_bf16<<<3072, 256, 0, stream>>>(wqkv, wqb, 786432);
  cvt_f32_bf16<<<1024, 256, 0, stream>>>(wout, owb, 262144);
  gemm_bt<0><<<dim3(32, 24), 256, 0, stream>>>(xb, wqb, bqkv, (void*)qkb, vtb,
                                               4096, 3072, 1024);
  attn_fwd<<<dim3(16, 32), 512, 0, stream>>>(qkb, vtb, abias, mask, aob);
  gemm_bt<1><<<dim3(32, 8), 256, 0, stream>>>(aob, owb, bout, d_out,
                                              (__hip_bfloat16*)nullptr, 4096, 1024, 1024);
}